// Round 7
// baseline (3713.140 us; speedup 1.0000x reference)
//
#include <hip/hip_runtime.h>
#include <hip/hip_bf16.h>
#include <math.h>

#define B_  32
#define N_  512
#define C_  384
#define H_  6
#define HD_ 64
#define M_  (B_*N_)   // 16384 rows

// ---------------- params ----------------
__global__ void param_kernel(const float* __restrict__ scale_p,
                             const float* __restrict__ power_p,
                             float* __restrict__ scale_inv,
                             float* __restrict__ power){
  int t = threadIdx.x;
  if (t < C_){
    float s  = scale_p[t];
    scale_inv[t] = 1.0f / log1pf(expf(s));   // 1/softplus
  }
  if (t < H_*HD_){
    float p = power_p[t];
    power[t] = 1.0f + 4.0f / (1.0f + expf(-p));
  }
}

// sentinel fill if input ordering ever mismatches expectations
__global__ void sentinel_kernel(float* __restrict__ out, int n){
  int i = blockIdx.x*256 + threadIdx.x;
  if (i < n) out[i] = 1.0e9f;
}

// featurize helper: returns (pos, neg) = (relu(x)^p, relu(-x)^p)
__device__ __forceinline__ void feat(float x, float p, float& pos, float& neg){
  float ax = fabsf(x);
  float pv = (ax > 0.0f) ? exp2f(p * log2f(ax)) : 0.0f;
  pos = (x > 0.0f) ? pv : 0.0f;
  neg = (x < 0.0f) ? pv : 0.0f;
}

// ---------------- qkvg GEMM (standard 64x64 tile, fp32) ----------------
__global__ __launch_bounds__(256) void gemm_qkvg(
    const float* __restrict__ x, const float* __restrict__ y,
    const float* __restrict__ W, const float* __restrict__ bias,
    const float* __restrict__ pe, const float* __restrict__ scale_inv,
    float* __restrict__ q, float* __restrict__ k, float* __restrict__ v,
    float* __restrict__ g)
{
  const int mode = blockIdx.z;
  const float* A = (mode == 0) ? y : x;
  const int wofs = mode * C_;
  float* out = (mode==0)?q:((mode==1)?k:((mode==2)?v:g));

  __shared__ __align__(16) float As[64][17];
  __shared__ __align__(16) float Bs[64][17];
  const int tid = threadIdx.x;
  const int tx = tid & 15, ty = tid >> 4;
  const int row0 = blockIdx.y * 64, col0 = blockIdx.x * 64;

  float acc[4][4] = {};
  const int flat = tid * 4;
  const int lr = flat >> 4, lk = flat & 15;

  for (int k0 = 0; k0 < C_; k0 += 16){
    const float4 av = *reinterpret_cast<const float4*>(&A[(size_t)(row0+lr)*C_ + k0 + lk]);
    const float4 bv = *reinterpret_cast<const float4*>(&W[(size_t)(wofs+col0+lr)*C_ + k0 + lk]);
    As[lr][lk+0]=av.x; As[lr][lk+1]=av.y; As[lr][lk+2]=av.z; As[lr][lk+3]=av.w;
    Bs[lr][lk+0]=bv.x; Bs[lr][lk+1]=bv.y; Bs[lr][lk+2]=bv.z; Bs[lr][lk+3]=bv.w;
    __syncthreads();
    #pragma unroll
    for (int kk = 0; kk < 16; kk++){
      float a0[4], b0[4];
      #pragma unroll
      for (int i=0;i<4;i++) a0[i] = As[ty*4+i][kk];
      #pragma unroll
      for (int j=0;j<4;j++) b0[j] = Bs[tx*4+j][kk];
      #pragma unroll
      for (int i=0;i<4;i++)
        #pragma unroll
        for (int j=0;j<4;j++)
          acc[i][j] = fmaf(a0[i], b0[j], acc[i][j]);
    }
    __syncthreads();
  }

  #pragma unroll
  for (int i=0;i<4;i++){
    const int row = row0 + ty*4 + i;
    const int n = row & (N_-1);
    const int colb = col0 + tx*4;
    float4 res; float* rp = &res.x;
    #pragma unroll
    for (int j=0;j<4;j++){
      const int col = colb + j;
      float val = acc[i][j] + bias[wofs+col];
      if (mode == 0)      val *= scale_inv[col];
      else if (mode == 1) val = (val + pe[n*C_+col]) * scale_inv[col];
      rp[j] = val;
    }
    *reinterpret_cast<float4*>(&out[(size_t)row*C_ + colb]) = res;
  }
}

// ---------------- attn stage A: kv[bh][d][e] and kmean[bh][d], brute force ----------------
__global__ __launch_bounds__(512) void attn_kv(
    const float* __restrict__ k, const float* __restrict__ v,
    const float* __restrict__ power,
    float* __restrict__ kvg, float* __restrict__ kmg)
{
  const int bh = blockIdx.x;
  const int b = bh / H_, h = bh % H_;
  const int tid = threadIdx.x;
  const float* kbase = k + (size_t)b*N_*C_ + h*HD_;
  const float* vbase = v + (size_t)b*N_*C_ + h*HD_;
  const float invN = 1.0f / (float)N_;

  for (int idx = tid; idx < 128*64; idx += 512){
    const int d = idx >> 6, e = idx & 63;
    const int c = d & 63;
    const bool neg_half = (d >= 64);
    const float p = power[h*HD_ + c];
    float acc = 0.0f;
    for (int n = 0; n < N_; n++){
      float kval = kbase[(size_t)n*C_ + c];
      float pos, neg; feat(kval, p, pos, neg);
      float kf = neg_half ? neg : pos;
      acc = fmaf(kf, vbase[(size_t)n*C_ + e], acc);
    }
    kvg[(size_t)bh*128*64 + idx] = acc * invN;
  }
  for (int d = tid; d < 128; d += 512){
    const int c = d & 63;
    const bool neg_half = (d >= 64);
    const float p = power[h*HD_ + c];
    float acc = 0.0f;
    for (int n = 0; n < N_; n++){
      float kval = kbase[(size_t)n*C_ + c];
      float pos, neg; feat(kval, p, pos, neg);
      acc += (neg_half ? neg : pos);
    }
    kmg[(size_t)bh*128 + d] = acc * invN;
  }
}

// ---------------- attn stage B ----------------
__global__ __launch_bounds__(512) void attn_xz(
    const float* __restrict__ q, const float* __restrict__ power,
    const float* __restrict__ kvg, const float* __restrict__ kmg,
    float* __restrict__ xa)
{
  const int bh = blockIdx.x;
  const int b = bh / H_, h = bh % H_;
  const int tid = threadIdx.x;
  const float* qbase = q + (size_t)b*N_*C_ + h*HD_;
  const float* kv = kvg + (size_t)bh*128*64;
  const float* km = kmg + (size_t)bh*128;
  float* xabase = xa + (size_t)b*N_*C_ + h*HD_;

  for (int idx = tid; idx < N_*64; idx += 512){
    const int n = idx >> 6, e = idx & 63;
    const bool opp = (e >= 32);
    float accx = 0.0f, accz = 0.0f;
    for (int D = 0; D < 128; D++){
      const int c = D & 63;
      const float p = power[h*HD_ + c];
      float qval = qbase[(size_t)n*C_ + c];
      float pos, neg; feat(qval, p, pos, neg);
      float qt;
      if (D < 64) qt = opp ? neg : pos;
      else        qt = opp ? pos : neg;
      accx = fmaf(qt, kv[D*64 + e], accx);
      accz = fmaf(qt, km[D], accz);
    }
    xabase[(size_t)n*C_ + e] = accx / (accz + 1e-6f);
  }
}

// ---------------- conv brute force, scrambled-destination accumulate ----------------
// vc flat-within-batch = h*N*HD + n*HD + ch  (reference's transpose+reshape quirk)
__global__ __launch_bounds__(512) void conv_bf(
    const float* __restrict__ v, const float* __restrict__ dwc_w,
    const float* __restrict__ dwc_b, float* __restrict__ xa)
{
  const int bh = blockIdx.x;
  const int b = bh / H_, h = bh % H_;
  const int tid = threadIdx.x;
  const float* vbase = v + (size_t)b*N_*C_ + h*HD_;
  float* xabatch = xa + (size_t)b*N_*C_ + (size_t)h*N_*HD_;

  for (int idx = tid; idx < N_*HD_; idx += 512){
    const int n = idx >> 6, ch = idx & 63;
    const int az = n >> 6, ay = (n >> 3) & 7, ax = n & 7;
    float s = dwc_b[ch];
    for (int kd = 0; kd < 5; kd++){
      const int zz = az + kd - 2;
      if ((unsigned)zz >= 8u) continue;
      for (int kh = 0; kh < 5; kh++){
        const int yy = ay + kh - 2;
        if ((unsigned)yy >= 8u) continue;
        const int basew = kd*25 + kh*5;
        for (int kw = 0; kw < 5; kw++){
          const int xx = ax + kw - 2;
          if ((unsigned)xx >= 8u) continue;
          const int nn = zz*64 + yy*8 + xx;
          s = fmaf(vbase[(size_t)nn*C_ + ch], dwc_w[ch*125 + basew + kw], s);
        }
      }
    }
    xabatch[(size_t)n*HD_ + ch] += s;   // one writer per element; attn_xz ran before
  }
}

// ---------------- proj GEMM: out = ((xa)*g) @ Wproj^T + bproj, FP32 out ----------------
__global__ __launch_bounds__(256) void proj_kernel(
    const float* __restrict__ xa, const float* __restrict__ g,
    const float* __restrict__ Wp, const float* __restrict__ bp,
    float* __restrict__ out)
{
  __shared__ __align__(16) float As[64][17];
  __shared__ __align__(16) float Bs[64][17];
  const int tid = threadIdx.x;
  const int tx = tid & 15, ty = tid >> 4;
  const int row0 = blockIdx.y*64, col0 = blockIdx.x*64;
  float acc[4][4] = {};
  const int flat = tid*4;
  const int lr = flat >> 4, lk = flat & 15;
  for (int k0 = 0; k0 < C_; k0 += 16){
    const size_t aidx = (size_t)(row0+lr)*C_ + k0 + lk;
    const float4 xv = *reinterpret_cast<const float4*>(&xa[aidx]);
    const float4 gv = *reinterpret_cast<const float4*>(&g[aidx]);
    const float4 bv = *reinterpret_cast<const float4*>(&Wp[(size_t)(col0+lr)*C_ + k0 + lk]);
    As[lr][lk+0]=xv.x*gv.x; As[lr][lk+1]=xv.y*gv.y; As[lr][lk+2]=xv.z*gv.z; As[lr][lk+3]=xv.w*gv.w;
    Bs[lr][lk+0]=bv.x; Bs[lr][lk+1]=bv.y; Bs[lr][lk+2]=bv.z; Bs[lr][lk+3]=bv.w;
    __syncthreads();
    #pragma unroll
    for (int kk = 0; kk < 16; kk++){
      float a0[4], b0[4];
      #pragma unroll
      for (int i=0;i<4;i++) a0[i] = As[ty*4+i][kk];
      #pragma unroll
      for (int j=0;j<4;j++) b0[j] = Bs[tx*4+j][kk];
      #pragma unroll
      for (int i=0;i<4;i++)
        #pragma unroll
        for (int j=0;j<4;j++)
          acc[i][j] = fmaf(a0[i], b0[j], acc[i][j]);
    }
    __syncthreads();
  }
  #pragma unroll
  for (int i=0;i<4;i++){
    const int row = row0 + ty*4 + i;
    const int colb = col0 + tx*4;
    float4 res;
    res.x = acc[i][0] + bp[colb+0];
    res.y = acc[i][1] + bp[colb+1];
    res.z = acc[i][2] + bp[colb+2];
    res.w = acc[i][3] + bp[colb+3];
    *reinterpret_cast<float4*>(&out[(size_t)row*C_ + colb]) = res;
  }
}

extern "C" void kernel_launch(void* const* d_in, const int* in_sizes, int n_in,
                              void* d_out, int out_size, void* d_ws, size_t ws_size,
                              hipStream_t stream){
  float* out = (float*)d_out;

  // guard: verify input ordering matches setup_inputs() dict order (deterministic branch)
  const int expect[11] = {6291456, 6291456, 589824, 1536, 147456, 384, 8000, 64, 384, 384, 196608};
  bool ok = (n_in == 11);
  for (int i = 0; ok && i < 11; i++) ok = (in_sizes[i] == expect[i]);
  if (!ok){
    sentinel_kernel<<<(out_size+255)/256, 256, 0, stream>>>(out, out_size);
    return;
  }

  const float* x    = (const float*)d_in[0];
  const float* y    = (const float*)d_in[1];
  const float* W    = (const float*)d_in[2];
  const float* bq   = (const float*)d_in[3];
  const float* Wp   = (const float*)d_in[4];
  const float* bp   = (const float*)d_in[5];
  const float* dwcw = (const float*)d_in[6];
  const float* dwcb = (const float*)d_in[7];
  const float* pwp  = (const float*)d_in[8];
  const float* scp  = (const float*)d_in[9];
  const float* pe   = (const float*)d_in[10];

  float* ws = (float*)d_ws;
  const size_t SZ = (size_t)M_ * C_;
  float* q  = ws;
  float* k  = ws + SZ;
  float* v  = ws + 2*SZ;
  float* g  = ws + 3*SZ;
  float* xa = ws + 4*SZ;
  float* kvg = ws + 5*SZ;                       // 192*128*64
  float* kmg = kvg + (size_t)B_*H_*128*64;      // 192*128
  float* scale_inv = kmg + (size_t)B_*H_*128;
  float* power     = scale_inv + 512;

  param_kernel<<<1, 512, 0, stream>>>(scp, pwp, scale_inv, power);
  gemm_qkvg<<<dim3(C_/64, M_/64, 4), 256, 0, stream>>>(x, y, W, bq, pe, scale_inv, q, k, v, g);
  attn_kv<<<dim3(B_*H_), 512, 0, stream>>>(k, v, power, kvg, kmg);
  attn_xz<<<dim3(B_*H_), 512, 0, stream>>>(q, power, kvg, kmg, xa);
  conv_bf<<<dim3(B_*H_), 512, 0, stream>>>(v, dwcw, dwcb, xa);
  proj_kernel<<<dim3(C_/64, M_/64), 256, 0, stream>>>(xa, g, Wp, bp, out);
}

// Round 8
// 1312.396 us; speedup vs baseline: 2.8293x; 2.8293x over previous
//
#include <hip/hip_runtime.h>
#include <hip/hip_bf16.h>
#include <math.h>

#define B_  32
#define N_  512
#define C_  384
#define H_  6
#define HD_ 64
#define M_  (B_*N_)   // 16384 rows

// ---------------- params ----------------
__global__ void param_kernel(const float* __restrict__ scale_p,
                             const float* __restrict__ power_p,
                             float* __restrict__ scale_inv,
                             float* __restrict__ power){
  int t = threadIdx.x;
  if (t < C_){
    float s  = scale_p[t];
    scale_inv[t] = 1.0f / log1pf(expf(s));   // 1/softplus
  }
  if (t < H_*HD_){
    float p = power_p[t];
    power[t] = 1.0f + 4.0f / (1.0f + expf(-p));
  }
}

// sentinel fill if input ordering ever mismatches expectations
__global__ void sentinel_kernel(float* __restrict__ out, int n){
  int i = blockIdx.x*256 + threadIdx.x;
  if (i < n) out[i] = 1.0e9f;
}

// ---------------- qkvg GEMM (standard 64x64 tile, fp32) ----------------
__global__ __launch_bounds__(256) void gemm_qkvg(
    const float* __restrict__ x, const float* __restrict__ y,
    const float* __restrict__ W, const float* __restrict__ bias,
    const float* __restrict__ pe, const float* __restrict__ scale_inv,
    float* __restrict__ q, float* __restrict__ k, float* __restrict__ v,
    float* __restrict__ g)
{
  const int mode = blockIdx.z;
  const float* A = (mode == 0) ? y : x;
  const int wofs = mode * C_;
  float* out = (mode==0)?q:((mode==1)?k:((mode==2)?v:g));

  __shared__ __align__(16) float As[64][17];
  __shared__ __align__(16) float Bs[64][17];
  const int tid = threadIdx.x;
  const int tx = tid & 15, ty = tid >> 4;
  const int row0 = blockIdx.y * 64, col0 = blockIdx.x * 64;

  float acc[4][4] = {};
  const int flat = tid * 4;
  const int lr = flat >> 4, lk = flat & 15;

  for (int k0 = 0; k0 < C_; k0 += 16){
    const float4 av = *reinterpret_cast<const float4*>(&A[(size_t)(row0+lr)*C_ + k0 + lk]);
    const float4 bv = *reinterpret_cast<const float4*>(&W[(size_t)(wofs+col0+lr)*C_ + k0 + lk]);
    As[lr][lk+0]=av.x; As[lr][lk+1]=av.y; As[lr][lk+2]=av.z; As[lr][lk+3]=av.w;
    Bs[lr][lk+0]=bv.x; Bs[lr][lk+1]=bv.y; Bs[lr][lk+2]=bv.z; Bs[lr][lk+3]=bv.w;
    __syncthreads();
    #pragma unroll
    for (int kk = 0; kk < 16; kk++){
      float a0[4], b0[4];
      #pragma unroll
      for (int i=0;i<4;i++) a0[i] = As[ty*4+i][kk];
      #pragma unroll
      for (int j=0;j<4;j++) b0[j] = Bs[tx*4+j][kk];
      #pragma unroll
      for (int i=0;i<4;i++)
        #pragma unroll
        for (int j=0;j<4;j++)
          acc[i][j] = fmaf(a0[i], b0[j], acc[i][j]);
    }
    __syncthreads();
  }

  #pragma unroll
  for (int i=0;i<4;i++){
    const int row = row0 + ty*4 + i;
    const int n = row & (N_-1);
    const int colb = col0 + tx*4;
    float4 res; float* rp = &res.x;
    #pragma unroll
    for (int j=0;j<4;j++){
      const int col = colb + j;
      float val = acc[i][j] + bias[wofs+col];
      if (mode == 0)      val *= scale_inv[col];
      else if (mode == 1) val = (val + pe[n*C_+col]) * scale_inv[col];
      rp[j] = val;
    }
    *reinterpret_cast<float4*>(&out[(size_t)row*C_ + colb]) = res;
  }
}

// ---------------- tiled attention: one block per (b,h), 512 threads ----------------
// Phase 1: featurize k once into LDS, accumulate kv (128x64) + kmean via register tiles.
// Phase 2: shuffle-broadcast q features, per-lane dot vs kvs/kmean (race-free).
__global__ __launch_bounds__(512) void attn_kernel(
    const float* __restrict__ q, const float* __restrict__ k,
    const float* __restrict__ v, const float* __restrict__ power,
    float* __restrict__ xa)
{
  const int bh = blockIdx.x;
  const int b = bh / H_, h = bh % H_;
  __shared__ __align__(16) float kf2[64][132];   // [n_local][d(0..127)]
  __shared__ __align__(16) float vs[64][72];     // [n_local][e(0..63)]
  __shared__ __align__(16) float kvs[128][66];   // kv[d][e], scaled by 1/N
  __shared__ float kmean[128];
  __shared__ float pw[64];
  const int tid = threadIdx.x;
  if (tid < 64)  pw[tid] = power[h*HD_ + tid];
  if (tid < 128) kmean[tid] = 0.0f;
  __syncthreads();

  const int dg = tid & 31;      // d block: 4*dg .. 4*dg+3
  const int eg = tid >> 5;      // e block: 4*eg .. 4*eg+3 (0..15)
  float acc[4][4] = {};
  const float* kbase = k + ((size_t)b*N_)*C_ + h*HD_;
  const float* vbase = v + ((size_t)b*N_)*C_ + h*HD_;

  for (int nc = 0; nc < 8; nc++){
    const int n0 = nc * 64;
    // featurize 64 n-rows of k, stage v chunk
    #pragma unroll
    for (int t = 0; t < 8; t++){
      const int flat = t*512 + tid;
      const int nl = flat >> 6, c = flat & 63;
      const float kval = kbase[(size_t)(n0+nl)*C_ + c];
      const float p  = pw[c];
      const float axv = fabsf(kval);
      const float pv = (axv > 0.0f) ? exp2f(p * log2f(axv)) : 0.0f;
      kf2[nl][c]      = (kval > 0.0f) ? pv : 0.0f;
      kf2[nl][64 + c] = (kval < 0.0f) ? pv : 0.0f;
      vs[nl][c] = vbase[(size_t)(n0+nl)*C_ + c];
    }
    __syncthreads();
    if (tid < 128){
      float s = 0.0f;
      for (int nl = 0; nl < 64; nl++) s += kf2[nl][tid];
      kmean[tid] += s;
    }
    // kv += kf^T @ v over this chunk
    for (int nl = 0; nl < 64; nl++){
      const float4 a4 = *reinterpret_cast<const float4*>(&kf2[nl][dg*4]);
      const float4 b4 = *reinterpret_cast<const float4*>(&vs[nl][eg*4]);
      const float a0[4] = {a4.x,a4.y,a4.z,a4.w};
      const float b0[4] = {b4.x,b4.y,b4.z,b4.w};
      #pragma unroll
      for (int i=0;i<4;i++)
        #pragma unroll
        for (int j=0;j<4;j++)
          acc[i][j] = fmaf(a0[i], b0[j], acc[i][j]);
    }
    __syncthreads();
  }
  const float invN = 1.0f / (float)N_;
  #pragma unroll
  for (int i=0;i<4;i++)
    #pragma unroll
    for (int j=0;j<4;j++)
      kvs[dg*4+i][eg*4+j] = acc[i][j] * invN;
  if (tid < 128) kmean[tid] *= invN;
  __syncthreads();
  // kvs/kmean now read-only.

  // phase 2: wave r owns rows n = nc*8 + r; q features broadcast via shuffles
  const int r = tid >> 6;          // wave id 0..7
  const int lane = tid & 63;
  const float* qbase = q + ((size_t)b*N_)*C_ + h*HD_;
  float* xabase = xa + ((size_t)b*N_)*C_ + h*HD_;
  const bool opp = (lane >= 32);
  const float p = pw[lane];
  for (int nc = 0; nc < 64; nc++){
    const int n = nc*8 + r;
    const float qv = qbase[(size_t)n*C_ + lane];
    const float axv = fabsf(qv);
    const float pv = (axv > 0.0f) ? exp2f(p * log2f(axv)) : 0.0f;
    const float vpos = (qv > 0.0f) ? pv : 0.0f;   // q_sim[lane]
    const float vneg = (qv < 0.0f) ? pv : 0.0f;   // q_sim[64+lane]
    float accx = 0.0f, accz = 0.0f;
    #pragma unroll 4
    for (int dd = 0; dd < 64; dd++){
      const float s0 = __shfl(vpos, dd);          // q_sim[dd]
      const float s1 = __shfl(vneg, dd);          // q_sim[64+dd]
      const float qlo = opp ? s1 : s0;            // q~[dd]
      const float qhi = opp ? s0 : s1;            // q~[64+dd]
      accx = fmaf(qlo, kvs[dd][lane],    accx);
      accx = fmaf(qhi, kvs[64+dd][lane], accx);
      accz = fmaf(qlo, kmean[dd],    accz);
      accz = fmaf(qhi, kmean[64+dd], accz);
    }
    xabase[(size_t)n*C_ + lane] = accx / (accz + 1e-6f);
  }
}

// ---------------- tiled depthwise 5x5x5 conv, scrambled-destination accumulate ----------------
// vc flat-within-batch = h*N*HD + n*HD + ch  (reference's transpose+reshape quirk)
__global__ __launch_bounds__(512) void conv_kernel(
    const float* __restrict__ v, const float* __restrict__ dwc_w,
    const float* __restrict__ dwc_b, float* __restrict__ xa)
{
  const int bh = blockIdx.x;
  const int b = bh / H_, h = bh % H_;
  __shared__ float vol[64][521];   // [ch][n], pad 521 to break conflicts
  __shared__ float wv[128];
  const int tid = threadIdx.x;
  const float* vbase = v + ((size_t)b*N_)*C_ + h*HD_;
  const int cl = tid & 63, ng = tid >> 6;
  for (int n0 = 0; n0 < N_; n0 += 8){
    const int n = n0 + ng;
    vol[cl][n] = vbase[(size_t)n*C_ + cl];
  }
  __syncthreads();
  const int n = tid;                       // one voxel per thread
  const int az = n >> 6, ay = (n >> 3) & 7, axc = n & 7;
  float* xabatch = xa + (size_t)b*N_*C_ + (size_t)h*N_*HD_;
  for (int ch = 0; ch < 64; ch++){
    if (tid < 125) wv[tid] = dwc_w[ch*125 + tid];
    if (tid == 125) wv[125] = dwc_b[ch];
    __syncthreads();
    float s = wv[125];
    #pragma unroll
    for (int kd = 0; kd < 5; kd++){
      const int zz = az + kd - 2;
      if ((unsigned)zz < 8u){
        #pragma unroll
        for (int kh = 0; kh < 5; kh++){
          const int yy = ay + kh - 2;
          if ((unsigned)yy < 8u){
            const int basev = zz*64 + yy*8;
            const int basew = kd*25 + kh*5;
            #pragma unroll
            for (int kw = 0; kw < 5; kw++){
              const int xx = axc + kw - 2;
              if ((unsigned)xx < 8u){
                s = fmaf(vol[ch][basev + xx], wv[basew + kw], s);
              }
            }
          }
        }
      }
    }
    __syncthreads();                       // protect wv before next-channel reload
    xabatch[(size_t)n*HD_ + ch] += s;      // one writer per element; attn ran before us
  }
}

// ---------------- proj GEMM: out = ((xa)*g) @ Wproj^T + bproj, FP32 out ----------------
__global__ __launch_bounds__(256) void proj_kernel(
    const float* __restrict__ xa, const float* __restrict__ g,
    const float* __restrict__ Wp, const float* __restrict__ bp,
    float* __restrict__ out)
{
  __shared__ __align__(16) float As[64][17];
  __shared__ __align__(16) float Bs[64][17];
  const int tid = threadIdx.x;
  const int tx = tid & 15, ty = tid >> 4;
  const int row0 = blockIdx.y*64, col0 = blockIdx.x*64;
  float acc[4][4] = {};
  const int flat = tid*4;
  const int lr = flat >> 4, lk = flat & 15;
  for (int k0 = 0; k0 < C_; k0 += 16){
    const size_t aidx = (size_t)(row0+lr)*C_ + k0 + lk;
    const float4 xv = *reinterpret_cast<const float4*>(&xa[aidx]);
    const float4 gv = *reinterpret_cast<const float4*>(&g[aidx]);
    const float4 bv = *reinterpret_cast<const float4*>(&Wp[(size_t)(col0+lr)*C_ + k0 + lk]);
    As[lr][lk+0]=xv.x*gv.x; As[lr][lk+1]=xv.y*gv.y; As[lr][lk+2]=xv.z*gv.z; As[lr][lk+3]=xv.w*gv.w;
    Bs[lr][lk+0]=bv.x; Bs[lr][lk+1]=bv.y; Bs[lr][lk+2]=bv.z; Bs[lr][lk+3]=bv.w;
    __syncthreads();
    #pragma unroll
    for (int kk = 0; kk < 16; kk++){
      float a0[4], b0[4];
      #pragma unroll
      for (int i=0;i<4;i++) a0[i] = As[ty*4+i][kk];
      #pragma unroll
      for (int j=0;j<4;j++) b0[j] = Bs[tx*4+j][kk];
      #pragma unroll
      for (int i=0;i<4;i++)
        #pragma unroll
        for (int j=0;j<4;j++)
          acc[i][j] = fmaf(a0[i], b0[j], acc[i][j]);
    }
    __syncthreads();
  }
  #pragma unroll
  for (int i=0;i<4;i++){
    const int row = row0 + ty*4 + i;
    const int colb = col0 + tx*4;
    float4 res;
    res.x = acc[i][0] + bp[colb+0];
    res.y = acc[i][1] + bp[colb+1];
    res.z = acc[i][2] + bp[colb+2];
    res.w = acc[i][3] + bp[colb+3];
    *reinterpret_cast<float4*>(&out[(size_t)row*C_ + colb]) = res;
  }
}

extern "C" void kernel_launch(void* const* d_in, const int* in_sizes, int n_in,
                              void* d_out, int out_size, void* d_ws, size_t ws_size,
                              hipStream_t stream){
  float* out = (float*)d_out;

  // guard: verify input ordering matches setup_inputs() dict order (deterministic branch)
  const int expect[11] = {6291456, 6291456, 589824, 1536, 147456, 384, 8000, 64, 384, 384, 196608};
  bool ok = (n_in == 11);
  for (int i = 0; ok && i < 11; i++) ok = (in_sizes[i] == expect[i]);
  if (!ok){
    sentinel_kernel<<<(out_size+255)/256, 256, 0, stream>>>(out, out_size);
    return;
  }

  const float* x    = (const float*)d_in[0];
  const float* y    = (const float*)d_in[1];
  const float* W    = (const float*)d_in[2];
  const float* bq   = (const float*)d_in[3];
  const float* Wp   = (const float*)d_in[4];
  const float* bp   = (const float*)d_in[5];
  const float* dwcw = (const float*)d_in[6];
  const float* dwcb = (const float*)d_in[7];
  const float* pwp  = (const float*)d_in[8];
  const float* scp  = (const float*)d_in[9];
  const float* pe   = (const float*)d_in[10];

  float* ws = (float*)d_ws;
  const size_t SZ = (size_t)M_ * C_;
  float* q  = ws;
  float* k  = ws + SZ;
  float* v  = ws + 2*SZ;
  float* g  = ws + 3*SZ;
  float* xa = ws + 4*SZ;
  float* scale_inv = ws + 5*SZ;
  float* power     = scale_inv + 512;

  param_kernel<<<1, 512, 0, stream>>>(scp, pwp, scale_inv, power);
  gemm_qkvg<<<dim3(C_/64, M_/64, 4), 256, 0, stream>>>(x, y, W, bq, pe, scale_inv, q, k, v, g);
  attn_kernel<<<dim3(B_*H_), 512, 0, stream>>>(q, k, v, power, xa);
  conv_kernel<<<dim3(B_*H_), 512, 0, stream>>>(v, dwcw, dwcb, xa);
  proj_kernel<<<dim3(C_/64, M_/64), 256, 0, stream>>>(xa, g, Wp, bp, out);
}

// Round 9
// 939.446 us; speedup vs baseline: 3.9525x; 1.3970x over previous
//
#include <hip/hip_runtime.h>
#include <hip/hip_bf16.h>
#include <math.h>

#define B_  32
#define N_  512
#define C_  384
#define H_  6
#define HD_ 64
#define M_  (B_*N_)   // 16384 rows

typedef __attribute__((ext_vector_type(8))) short bfrag;   // 8 bf16 (4 VGPRs)
typedef __attribute__((ext_vector_type(4))) float f32x4;   // mfma C/D

__device__ __forceinline__ unsigned short f2bfu(float f){
  unsigned int u = __float_as_uint(f);
  u += 0x7fffu + ((u >> 16) & 1u);   // round-to-nearest-even
  return (unsigned short)(u >> 16);
}
__device__ __forceinline__ bfrag cvt8(float4 a, float4 b){
  bfrag r;
  r[0]=(short)f2bfu(a.x); r[1]=(short)f2bfu(a.y); r[2]=(short)f2bfu(a.z); r[3]=(short)f2bfu(a.w);
  r[4]=(short)f2bfu(b.x); r[5]=(short)f2bfu(b.y); r[6]=(short)f2bfu(b.z); r[7]=(short)f2bfu(b.w);
  return r;
}

// ---------------- params ----------------
__global__ void param_kernel(const float* __restrict__ scale_p,
                             const float* __restrict__ power_p,
                             float* __restrict__ scale_inv,
                             float* __restrict__ power){
  int t = threadIdx.x;
  if (t < C_){
    float s  = scale_p[t];
    scale_inv[t] = 1.0f / log1pf(expf(s));   // 1/softplus
  }
  if (t < H_*HD_){
    float p = power_p[t];
    power[t] = 1.0f + 4.0f / (1.0f + expf(-p));
  }
}

// sentinel fill if input ordering ever mismatches expectations
__global__ void sentinel_kernel(float* __restrict__ out, int n){
  int i = blockIdx.x*256 + threadIdx.x;
  if (i < n) out[i] = 1.0e9f;
}

// ---------------- qkvg GEMM, MFMA bf16: 128x128 tile, 4 waves (2x2) ----------------
// mode 0: q = (y @ W0^T + b0) * scale_inv
// mode 1: k = ((x @ W1^T + b1) + pe) * scale_inv
// mode 2: v =  x @ W2^T + b2
// mode 3: g =  x @ W3^T + b3
__global__ __launch_bounds__(256) void gemm_qkvg(
    const float* __restrict__ x, const float* __restrict__ y,
    const float* __restrict__ W, const float* __restrict__ bias,
    const float* __restrict__ pe, const float* __restrict__ scale_inv,
    float* __restrict__ q, float* __restrict__ k, float* __restrict__ v,
    float* __restrict__ g)
{
  const int mode = blockIdx.z;
  const float* A = (mode == 0) ? y : x;
  const int wofs = mode * C_;
  float* out = (mode==0)?q:((mode==1)?k:((mode==2)?v:g));

  __shared__ short As[128][40];   // pad 40: 80B row stride = 5*16B (aligned, 2-way banks)
  __shared__ short Bs[128][40];

  const int tid  = threadIdx.x;
  const int row0 = blockIdx.y * 128;
  const int col0 = blockIdx.x * 128;
  const int wave = tid >> 6, lane = tid & 63;
  const int wm = (wave >> 1) * 64, wn = (wave & 1) * 64;
  const int fr = lane & 15, quad = lane >> 4;

  const int sr = tid >> 2;            // staging row 0..63 (+64)
  const int sk = (tid & 3) * 8;       // staging k chunk

  f32x4 acc[4][4] = {};

  for (int k0 = 0; k0 < C_; k0 += 32){
    #pragma unroll
    for (int half = 0; half < 2; half++){
      const int r = sr + half*64;
      const float* ap = &A[(size_t)(row0 + r)*C_ + k0 + sk];
      const float* bp = &W[(size_t)(wofs + col0 + r)*C_ + k0 + sk];
      float4 a0 = *reinterpret_cast<const float4*>(ap);
      float4 a1 = *reinterpret_cast<const float4*>(ap + 4);
      float4 b0 = *reinterpret_cast<const float4*>(bp);
      float4 b1 = *reinterpret_cast<const float4*>(bp + 4);
      *reinterpret_cast<bfrag*>(&As[r][sk]) = cvt8(a0, a1);
      *reinterpret_cast<bfrag*>(&Bs[r][sk]) = cvt8(b0, b1);
    }
    __syncthreads();
    bfrag af[4], bf[4];
    #pragma unroll
    for (int f = 0; f < 4; f++){
      af[f] = *reinterpret_cast<const bfrag*>(&As[wm + f*16 + fr][quad*8]);
      bf[f] = *reinterpret_cast<const bfrag*>(&Bs[wn + f*16 + fr][quad*8]);
    }
    #pragma unroll
    for (int i=0;i<4;i++)
      #pragma unroll
      for (int j=0;j<4;j++)
        acc[i][j] = __builtin_amdgcn_mfma_f32_16x16x32_bf16(af[i], bf[j], acc[i][j], 0, 0, 0);
    __syncthreads();
  }

  // epilogue: D col=lane&15, row=quad*4+reg
  #pragma unroll
  for (int i = 0; i < 4; i++){
    const int rowb = row0 + wm + i*16 + quad*4;
    #pragma unroll
    for (int j = 0; j < 4; j++){
      const int col = col0 + wn + j*16 + fr;
      const float bcol = bias[wofs + col];
      const float sc   = scale_inv[col];
      #pragma unroll
      for (int r = 0; r < 4; r++){
        const int row = rowb + r;
        const int n = row & (N_-1);
        float val = acc[i][j][r] + bcol;
        if (mode == 0)      val *= sc;
        else if (mode == 1) val = (val + pe[n*C_ + col]) * sc;
        out[(size_t)row*C_ + col] = val;
      }
    }
  }
}

// ---------------- tiled attention: one block per (b,h), 512 threads ----------------
__global__ __launch_bounds__(512) void attn_kernel(
    const float* __restrict__ q, const float* __restrict__ k,
    const float* __restrict__ v, const float* __restrict__ power,
    float* __restrict__ xa)
{
  const int bh = blockIdx.x;
  const int b = bh / H_, h = bh % H_;
  __shared__ __align__(16) float kf2[64][132];   // [n_local][d(0..127)]
  __shared__ __align__(16) float vs[64][72];     // [n_local][e(0..63)]
  __shared__ __align__(16) float kvs[128][66];   // kv[d][e], scaled by 1/N
  __shared__ float kmean[128];
  __shared__ float pw[64];
  const int tid = threadIdx.x;
  if (tid < 64)  pw[tid] = power[h*HD_ + tid];
  if (tid < 128) kmean[tid] = 0.0f;
  __syncthreads();

  const int dg = tid & 31;
  const int eg = tid >> 5;
  float acc[4][4] = {};
  const float* kbase = k + ((size_t)b*N_)*C_ + h*HD_;
  const float* vbase = v + ((size_t)b*N_)*C_ + h*HD_;

  for (int nc = 0; nc < 8; nc++){
    const int n0 = nc * 64;
    #pragma unroll
    for (int t = 0; t < 8; t++){
      const int flat = t*512 + tid;
      const int nl = flat >> 6, c = flat & 63;
      const float kval = kbase[(size_t)(n0+nl)*C_ + c];
      const float p  = pw[c];
      const float axv = fabsf(kval);
      const float pv = (axv > 0.0f) ? exp2f(p * log2f(axv)) : 0.0f;
      kf2[nl][c]      = (kval > 0.0f) ? pv : 0.0f;
      kf2[nl][64 + c] = (kval < 0.0f) ? pv : 0.0f;
      vs[nl][c] = vbase[(size_t)(n0+nl)*C_ + c];
    }
    __syncthreads();
    if (tid < 128){
      float s = 0.0f;
      for (int nl = 0; nl < 64; nl++) s += kf2[nl][tid];
      kmean[tid] += s;
    }
    for (int nl = 0; nl < 64; nl++){
      const float4 a4 = *reinterpret_cast<const float4*>(&kf2[nl][dg*4]);
      const float4 b4 = *reinterpret_cast<const float4*>(&vs[nl][eg*4]);
      const float a0[4] = {a4.x,a4.y,a4.z,a4.w};
      const float b0[4] = {b4.x,b4.y,b4.z,b4.w};
      #pragma unroll
      for (int i=0;i<4;i++)
        #pragma unroll
        for (int j=0;j<4;j++)
          acc[i][j] = fmaf(a0[i], b0[j], acc[i][j]);
    }
    __syncthreads();
  }
  const float invN = 1.0f / (float)N_;
  #pragma unroll
  for (int i=0;i<4;i++)
    #pragma unroll
    for (int j=0;j<4;j++)
      kvs[dg*4+i][eg*4+j] = acc[i][j] * invN;
  if (tid < 128) kmean[tid] *= invN;
  __syncthreads();

  const int r = tid >> 6;
  const int lane = tid & 63;
  const float* qbase = q + ((size_t)b*N_)*C_ + h*HD_;
  float* xabase = xa + ((size_t)b*N_)*C_ + h*HD_;
  const bool opp = (lane >= 32);
  const float p = pw[lane];
  for (int nc = 0; nc < 64; nc++){
    const int n = nc*8 + r;
    const float qv = qbase[(size_t)n*C_ + lane];
    const float axv = fabsf(qv);
    const float pv = (axv > 0.0f) ? exp2f(p * log2f(axv)) : 0.0f;
    const float vpos = (qv > 0.0f) ? pv : 0.0f;
    const float vneg = (qv < 0.0f) ? pv : 0.0f;
    float accx = 0.0f, accz = 0.0f;
    #pragma unroll 4
    for (int dd = 0; dd < 64; dd++){
      const float s0 = __shfl(vpos, dd);
      const float s1 = __shfl(vneg, dd);
      const float qlo = opp ? s1 : s0;
      const float qhi = opp ? s0 : s1;
      accx = fmaf(qlo, kvs[dd][lane],    accx);
      accx = fmaf(qhi, kvs[64+dd][lane], accx);
      accz = fmaf(qlo, kmean[dd],    accz);
      accz = fmaf(qhi, kmean[64+dd], accz);
    }
    xabase[(size_t)n*C_ + lane] = accx / (accz + 1e-6f);
  }
}

// ---------------- tiled depthwise 5x5x5 conv, scrambled-destination accumulate ----------------
__global__ __launch_bounds__(512) void conv_kernel(
    const float* __restrict__ v, const float* __restrict__ dwc_w,
    const float* __restrict__ dwc_b, float* __restrict__ xa)
{
  const int bh = blockIdx.x;
  const int b = bh / H_, h = bh % H_;
  __shared__ float vol[64][521];
  __shared__ float wv[128];
  const int tid = threadIdx.x;
  const float* vbase = v + ((size_t)b*N_)*C_ + h*HD_;
  const int cl = tid & 63, ng = tid >> 6;
  for (int n0 = 0; n0 < N_; n0 += 8){
    const int n = n0 + ng;
    vol[cl][n] = vbase[(size_t)n*C_ + cl];
  }
  __syncthreads();
  const int n = tid;
  const int az = n >> 6, ay = (n >> 3) & 7, axc = n & 7;
  float* xabatch = xa + (size_t)b*N_*C_ + (size_t)h*N_*HD_;
  for (int ch = 0; ch < 64; ch++){
    if (tid < 125) wv[tid] = dwc_w[ch*125 + tid];
    if (tid == 125) wv[125] = dwc_b[ch];
    __syncthreads();
    float s = wv[125];
    #pragma unroll
    for (int kd = 0; kd < 5; kd++){
      const int zz = az + kd - 2;
      if ((unsigned)zz < 8u){
        #pragma unroll
        for (int kh = 0; kh < 5; kh++){
          const int yy = ay + kh - 2;
          if ((unsigned)yy < 8u){
            const int basev = zz*64 + yy*8;
            const int basew = kd*25 + kh*5;
            #pragma unroll
            for (int kw = 0; kw < 5; kw++){
              const int xx = axc + kw - 2;
              if ((unsigned)xx < 8u){
                s = fmaf(vol[ch][basev + xx], wv[basew + kw], s);
              }
            }
          }
        }
      }
    }
    __syncthreads();
    xabatch[(size_t)n*HD_ + ch] += s;
  }
}

// ---------------- proj GEMM, MFMA bf16: out = ((xa)*g) @ Wproj^T + bproj, fp32 out ----------------
__global__ __launch_bounds__(256) void proj_kernel(
    const float* __restrict__ xa, const float* __restrict__ g,
    const float* __restrict__ Wp, const float* __restrict__ bp,
    float* __restrict__ out)
{
  __shared__ short As[128][40];
  __shared__ short Bs[128][40];

  const int tid  = threadIdx.x;
  const int row0 = blockIdx.y * 128;
  const int col0 = blockIdx.x * 128;
  const int wave = tid >> 6, lane = tid & 63;
  const int wm = (wave >> 1) * 64, wn = (wave & 1) * 64;
  const int fr = lane & 15, quad = lane >> 4;
  const int sr = tid >> 2;
  const int sk = (tid & 3) * 8;

  f32x4 acc[4][4] = {};

  for (int k0 = 0; k0 < C_; k0 += 32){
    #pragma unroll
    for (int half = 0; half < 2; half++){
      const int r = sr + half*64;
      const size_t aidx = (size_t)(row0 + r)*C_ + k0 + sk;
      float4 x0 = *reinterpret_cast<const float4*>(&xa[aidx]);
      float4 x1 = *reinterpret_cast<const float4*>(&xa[aidx + 4]);
      float4 g0 = *reinterpret_cast<const float4*>(&g[aidx]);
      float4 g1 = *reinterpret_cast<const float4*>(&g[aidx + 4]);
      x0.x*=g0.x; x0.y*=g0.y; x0.z*=g0.z; x0.w*=g0.w;
      x1.x*=g1.x; x1.y*=g1.y; x1.z*=g1.z; x1.w*=g1.w;
      const float* bp2 = &Wp[(size_t)(col0 + r)*C_ + k0 + sk];
      float4 b0 = *reinterpret_cast<const float4*>(bp2);
      float4 b1 = *reinterpret_cast<const float4*>(bp2 + 4);
      *reinterpret_cast<bfrag*>(&As[r][sk]) = cvt8(x0, x1);
      *reinterpret_cast<bfrag*>(&Bs[r][sk]) = cvt8(b0, b1);
    }
    __syncthreads();
    bfrag af[4], bf[4];
    #pragma unroll
    for (int f = 0; f < 4; f++){
      af[f] = *reinterpret_cast<const bfrag*>(&As[wm + f*16 + fr][quad*8]);
      bf[f] = *reinterpret_cast<const bfrag*>(&Bs[wn + f*16 + fr][quad*8]);
    }
    #pragma unroll
    for (int i=0;i<4;i++)
      #pragma unroll
      for (int j=0;j<4;j++)
        acc[i][j] = __builtin_amdgcn_mfma_f32_16x16x32_bf16(af[i], bf[j], acc[i][j], 0, 0, 0);
    __syncthreads();
  }

  #pragma unroll
  for (int i = 0; i < 4; i++){
    const int rowb = row0 + wm + i*16 + quad*4;
    #pragma unroll
    for (int j = 0; j < 4; j++){
      const int col = col0 + wn + j*16 + fr;
      const float bcol = bp[col];
      #pragma unroll
      for (int r = 0; r < 4; r++){
        out[(size_t)(rowb + r)*C_ + col] = acc[i][j][r] + bcol;
      }
    }
  }
}

extern "C" void kernel_launch(void* const* d_in, const int* in_sizes, int n_in,
                              void* d_out, int out_size, void* d_ws, size_t ws_size,
                              hipStream_t stream){
  float* out = (float*)d_out;

  const int expect[11] = {6291456, 6291456, 589824, 1536, 147456, 384, 8000, 64, 384, 384, 196608};
  bool ok = (n_in == 11);
  for (int i = 0; ok && i < 11; i++) ok = (in_sizes[i] == expect[i]);
  if (!ok){
    sentinel_kernel<<<(out_size+255)/256, 256, 0, stream>>>(out, out_size);
    return;
  }

  const float* x    = (const float*)d_in[0];
  const float* y    = (const float*)d_in[1];
  const float* W    = (const float*)d_in[2];
  const float* bq   = (const float*)d_in[3];
  const float* Wp   = (const float*)d_in[4];
  const float* bp   = (const float*)d_in[5];
  const float* dwcw = (const float*)d_in[6];
  const float* dwcb = (const float*)d_in[7];
  const float* pwp  = (const float*)d_in[8];
  const float* scp  = (const float*)d_in[9];
  const float* pe   = (const float*)d_in[10];

  float* ws = (float*)d_ws;
  const size_t SZ = (size_t)M_ * C_;
  float* q  = ws;
  float* k  = ws + SZ;
  float* v  = ws + 2*SZ;
  float* g  = ws + 3*SZ;
  float* xa = ws + 4*SZ;
  float* scale_inv = ws + 5*SZ;
  float* power     = scale_inv + 512;

  param_kernel<<<1, 512, 0, stream>>>(scp, pwp, scale_inv, power);
  gemm_qkvg<<<dim3(C_/128, M_/128, 4), 256, 0, stream>>>(x, y, W, bq, pe, scale_inv, q, k, v, g);
  attn_kernel<<<dim3(B_*H_), 512, 0, stream>>>(q, k, v, power, xa);
  conv_kernel<<<dim3(B_*H_), 512, 0, stream>>>(v, dwcw, dwcb, xa);
  proj_kernel<<<dim3(C_/128, M_/128), 256, 0, stream>>>(xa, g, Wp, bp, out);
}

// Round 10
// 279.842 us; speedup vs baseline: 13.2687x; 3.3571x over previous
//
#include <hip/hip_runtime.h>
#include <hip/hip_bf16.h>
#include <math.h>

#define B_  32
#define N_  512
#define C_  384
#define H_  6
#define HD_ 64
#define M_  (B_*N_)   // 16384 rows

typedef __attribute__((ext_vector_type(8))) short bfrag;   // 8 bf16 (4 VGPRs)
typedef __attribute__((ext_vector_type(4))) float f32x4;   // mfma C/D

__device__ __forceinline__ unsigned short f2bfu(float f){
  unsigned int u = __float_as_uint(f);
  u += 0x7fffu + ((u >> 16) & 1u);   // round-to-nearest-even
  return (unsigned short)(u >> 16);
}
__device__ __forceinline__ bfrag cvt8(float4 a, float4 b){
  bfrag r;
  r[0]=(short)f2bfu(a.x); r[1]=(short)f2bfu(a.y); r[2]=(short)f2bfu(a.z); r[3]=(short)f2bfu(a.w);
  r[4]=(short)f2bfu(b.x); r[5]=(short)f2bfu(b.y); r[6]=(short)f2bfu(b.z); r[7]=(short)f2bfu(b.w);
  return r;
}

// ---------------- params ----------------
__global__ void param_kernel(const float* __restrict__ scale_p,
                             const float* __restrict__ power_p,
                             float* __restrict__ scale_inv,
                             float* __restrict__ power){
  int t = threadIdx.x;
  if (t < C_){
    float s  = scale_p[t];
    scale_inv[t] = 1.0f / log1pf(expf(s));   // 1/softplus
  }
  if (t < H_*HD_){
    float p = power_p[t];
    power[t] = 1.0f + 4.0f / (1.0f + expf(-p));
  }
}

__global__ void sentinel_kernel(float* __restrict__ out, int n){
  int i = blockIdx.x*256 + threadIdx.x;
  if (i < n) out[i] = 1.0e9f;
}

// ---------------- qkvg GEMM, MFMA bf16 (unchanged from r9) ----------------
__global__ __launch_bounds__(256) void gemm_qkvg(
    const float* __restrict__ x, const float* __restrict__ y,
    const float* __restrict__ W, const float* __restrict__ bias,
    const float* __restrict__ pe, const float* __restrict__ scale_inv,
    float* __restrict__ q, float* __restrict__ k, float* __restrict__ v,
    float* __restrict__ g)
{
  const int mode = blockIdx.z;
  const float* A = (mode == 0) ? y : x;
  const int wofs = mode * C_;
  float* out = (mode==0)?q:((mode==1)?k:((mode==2)?v:g));

  __shared__ short As[128][40];
  __shared__ short Bs[128][40];

  const int tid  = threadIdx.x;
  const int row0 = blockIdx.y * 128;
  const int col0 = blockIdx.x * 128;
  const int wave = tid >> 6, lane = tid & 63;
  const int wm = (wave >> 1) * 64, wn = (wave & 1) * 64;
  const int fr = lane & 15, quad = lane >> 4;
  const int sr = tid >> 2;
  const int sk = (tid & 3) * 8;

  f32x4 acc[4][4] = {};

  for (int k0 = 0; k0 < C_; k0 += 32){
    #pragma unroll
    for (int half = 0; half < 2; half++){
      const int r = sr + half*64;
      const float* ap = &A[(size_t)(row0 + r)*C_ + k0 + sk];
      const float* bp = &W[(size_t)(wofs + col0 + r)*C_ + k0 + sk];
      float4 a0 = *reinterpret_cast<const float4*>(ap);
      float4 a1 = *reinterpret_cast<const float4*>(ap + 4);
      float4 b0 = *reinterpret_cast<const float4*>(bp);
      float4 b1 = *reinterpret_cast<const float4*>(bp + 4);
      *reinterpret_cast<bfrag*>(&As[r][sk]) = cvt8(a0, a1);
      *reinterpret_cast<bfrag*>(&Bs[r][sk]) = cvt8(b0, b1);
    }
    __syncthreads();
    bfrag af[4], bf[4];
    #pragma unroll
    for (int f = 0; f < 4; f++){
      af[f] = *reinterpret_cast<const bfrag*>(&As[wm + f*16 + fr][quad*8]);
      bf[f] = *reinterpret_cast<const bfrag*>(&Bs[wn + f*16 + fr][quad*8]);
    }
    #pragma unroll
    for (int i=0;i<4;i++)
      #pragma unroll
      for (int j=0;j<4;j++)
        acc[i][j] = __builtin_amdgcn_mfma_f32_16x16x32_bf16(af[i], bf[j], acc[i][j], 0, 0, 0);
    __syncthreads();
  }

  #pragma unroll
  for (int i = 0; i < 4; i++){
    const int rowb = row0 + wm + i*16 + quad*4;
    #pragma unroll
    for (int j = 0; j < 4; j++){
      const int col = col0 + wn + j*16 + fr;
      const float bcol = bias[wofs + col];
      const float sc   = scale_inv[col];
      #pragma unroll
      for (int r = 0; r < 4; r++){
        const int row = rowb + r;
        const int n = row & (N_-1);
        float val = acc[i][j][r] + bcol;
        if (mode == 0)      val *= sc;
        else if (mode == 1) val = (val + pe[n*C_ + col]) * sc;
        out[(size_t)row*C_ + col] = val;
      }
    }
  }
}

// ---------------- attention, MFMA: one block per (b,h), 512 threads (8 waves) ----------------
// Phase 1: kv(128x80) = kfT(128x512) @ [v | ones | 0](512x80); col64 = sum kf = N*kmean.
// kvBT[e][d] = (e<32 ? kv[d][e] : kv[d^64][e]) * invN ; rows 64/65 = km[d], km[d^64].
// Phase 2: X(512x80) = qf_sim(512x128) @ kvBT^T-sense; cols0..63 = x, col64/65 = z_sim/z_opp.
#define NC_ 256
__global__ __launch_bounds__(512) void attn_kernel(
    const float* __restrict__ q, const float* __restrict__ k,
    const float* __restrict__ v, const float* __restrict__ power,
    float* __restrict__ xa)
{
  const int bh = blockIdx.x;
  const int b = bh / H_, h = bh % H_;
  __shared__ float pw[64];
  __shared__ __align__(16) unsigned short smem[54912];  // 109,824 B
  unsigned short* kfT  = smem;                  // [128][264] phase A
  unsigned short* vT   = smem + 33792;          // [80][264]  phase A
  unsigned short* kvBT = smem;                  // [80][136]  phase B (alias)
  unsigned short* qf   = smem + 33792;          // [128][136] phase B (alias)

  const int tid = threadIdx.x;
  const int wave = tid >> 6, lane = tid & 63;
  const int fr = lane & 15, quad = lane >> 4;
  if (tid < 64) pw[tid] = power[h*HD_ + tid];

  const float* kbase = k + (size_t)b*N_*C_ + h*HD_;
  const float* vbase = v + (size_t)b*N_*C_ + h*HD_;

  // init vT rows 64..79 (ones column + zeros) — persists across both chunks
  for (int i = tid; i < 16*NC_; i += 512){
    int e = 64 + (i >> 8);
    int nl = i & (NC_-1);
    vT[e*264 + nl] = (e == 64) ? (unsigned short)0x3F80 : (unsigned short)0;
  }
  __syncthreads();

  f32x4 acc[5] = {};
  for (int chunk = 0; chunk < 2; chunk++){
    const int n0 = chunk * NC_;
    for (int it = 0; it < 32; it++){
      int flat = it*512 + tid;
      int c = flat & 63, nl = flat >> 6;
      float kval = kbase[(size_t)(n0+nl)*C_ + c];
      float p = pw[c];
      float ax = fabsf(kval);
      float pv = (ax > 0.0f) ? exp2f(p * log2f(ax)) : 0.0f;
      kfT[c*264 + nl]      = f2bfu((kval > 0.0f) ? pv : 0.0f);
      kfT[(64+c)*264 + nl] = f2bfu((kval < 0.0f) ? pv : 0.0f);
      vT[c*264 + nl] = f2bfu(vbase[(size_t)(n0+nl)*C_ + c]);
    }
    __syncthreads();
    for (int kk = 0; kk < NC_/32; kk++){
      int ko = kk*32 + quad*8;
      bfrag af = *reinterpret_cast<const bfrag*>(&kfT[(wave*16 + fr)*264 + ko]);
      #pragma unroll
      for (int j = 0; j < 5; j++){
        bfrag bf = *reinterpret_cast<const bfrag*>(&vT[(j*16 + fr)*264 + ko]);
        acc[j] = __builtin_amdgcn_mfma_f32_16x16x32_bf16(af, bf, acc[j], 0, 0, 0);
      }
    }
    __syncthreads();
  }

  // write kvBT (scaled), with d^64 flip for e>=32; rows 64/65 = z-vectors
  const float invN = 1.0f / (float)N_;
  {
    const int dbase = wave*16 + quad*4;
    #pragma unroll
    for (int j = 0; j < 4; j++){
      const int e = j*16 + fr;
      const int dd = (e < 32) ? dbase : (dbase ^ 64);
      ushort4 w4;
      w4.x = f2bfu(acc[j][0] * invN);
      w4.y = f2bfu(acc[j][1] * invN);
      w4.z = f2bfu(acc[j][2] * invN);
      w4.w = f2bfu(acc[j][3] * invN);
      *reinterpret_cast<ushort4*>(&kvBT[e*136 + dd]) = w4;
    }
    if (fr == 0){
      ushort4 wk;
      wk.x = f2bfu(acc[4][0] * invN);
      wk.y = f2bfu(acc[4][1] * invN);
      wk.z = f2bfu(acc[4][2] * invN);
      wk.w = f2bfu(acc[4][3] * invN);
      *reinterpret_cast<ushort4*>(&kvBT[64*136 + dbase]) = wk;          // km[d]
      *reinterpret_cast<ushort4*>(&kvBT[65*136 + (dbase^64)]) = wk;     // km at flipped d
    }
  }
  __syncthreads();

  // phase B: 4 m-chunks of 128 rows
  const float* qbase = q + (size_t)b*N_*C_ + h*HD_;
  float* xabase = xa + (size_t)b*N_*C_ + h*HD_;
  for (int mc = 0; mc < 4; mc++){
    const int m0 = mc * 128;
    for (int it = 0; it < 16; it++){
      int flat = it*512 + tid;
      int c = flat & 63, nl = flat >> 6;
      float qval = qbase[(size_t)(m0+nl)*C_ + c];
      float p = pw[c];
      float ax = fabsf(qval);
      float pv = (ax > 0.0f) ? exp2f(p * log2f(ax)) : 0.0f;
      qf[nl*136 + c]      = f2bfu((qval > 0.0f) ? pv : 0.0f);
      qf[nl*136 + 64 + c] = f2bfu((qval < 0.0f) ? pv : 0.0f);
    }
    __syncthreads();
    f32x4 a2[5] = {};
    for (int kk = 0; kk < 4; kk++){
      int ko = kk*32 + quad*8;
      bfrag af = *reinterpret_cast<const bfrag*>(&qf[(wave*16 + fr)*136 + ko]);
      #pragma unroll
      for (int j = 0; j < 5; j++){
        bfrag bf = *reinterpret_cast<const bfrag*>(&kvBT[(j*16 + fr)*136 + ko]);
        a2[j] = __builtin_amdgcn_mfma_f32_16x16x32_bf16(af, bf, a2[j], 0, 0, 0);
      }
    }
    #pragma unroll
    for (int r = 0; r < 4; r++){
      const float zsim = __shfl(a2[4][r], quad*16);
      const float zopp = __shfl(a2[4][r], quad*16 + 1);
      const int n = m0 + wave*16 + quad*4 + r;
      #pragma unroll
      for (int j = 0; j < 4; j++){
        const int e = j*16 + fr;
        const float z = (e < 32) ? zsim : zopp;
        xabase[(size_t)n*C_ + e] = a2[j][r] / (z + 1e-6f);
      }
    }
    __syncthreads();   // before next m-chunk overwrites qf
  }
}

// ---------------- conv: ch-halves, 8-wide x-rows in registers, coalesced RMW ----------------
// vc flat-within-batch = h*N*HD + n*HD + ch  (reference's transpose+reshape quirk)
__global__ __launch_bounds__(512) void conv_kernel(
    const float* __restrict__ v, const float* __restrict__ dwc_w,
    const float* __restrict__ dwc_b, float* __restrict__ xa)
{
  const int bh = blockIdx.x;
  const int b = bh / H_, h = bh % H_;
  __shared__ float vol[32][521];   // 66.7 KB
  __shared__ float wv[32][126];    // 16.1 KB
  __shared__ float wb[32];
  const int tid = threadIdx.x;
  const float* vbase = v + (size_t)b*N_*C_ + h*HD_;
  float* xabatch = xa + (size_t)b*N_*C_ + (size_t)h*N_*HD_;

  for (int half = 0; half < 2; half++){
    const int ch0 = half * 32;
    // stage v half: 32 ch x 512 n
    for (int it = 0; it < 32; it++){
      int flat = it*512 + tid;
      int cl = flat & 31, n = flat >> 5;
      vol[cl][n] = vbase[(size_t)n*C_ + ch0 + cl];
    }
    // stage weights
    for (int i = tid; i < 32*125; i += 512){
      int ch = i / 125, wi = i - ch*125;
      wv[ch][wi] = dwc_w[(ch0+ch)*125 + wi];
    }
    if (tid < 32) wb[tid] = dwc_b[ch0 + tid];
    __syncthreads();

    for (int t = 0; t < 4; t++){
      const int task = t*512 + tid;
      const int ch = task & 31;
      const int zy = task >> 5;          // 0..63
      const int z = zy >> 3, yc = zy & 7;
      float o[8];
      const float bias = wb[ch];
      #pragma unroll
      for (int xx = 0; xx < 8; xx++) o[xx] = bias;
      #pragma unroll
      for (int kd = 0; kd < 5; kd++){
        const int zz = z + kd - 2;
        if ((unsigned)zz >= 8u) continue;
        #pragma unroll
        for (int kh = 0; kh < 5; kh++){
          const int yy = yc + kh - 2;
          if ((unsigned)yy >= 8u) continue;
          const float* row = &vol[ch][zz*64 + yy*8];
          float rr[8];
          #pragma unroll
          for (int xx = 0; xx < 8; xx++) rr[xx] = row[xx];
          const float* wrow = &wv[ch][kd*25 + kh*5];
          float w5[5];
          #pragma unroll
          for (int kw = 0; kw < 5; kw++) w5[kw] = wrow[kw];
          #pragma unroll
          for (int xx = 0; xx < 8; xx++){
            #pragma unroll
            for (int kw = 0; kw < 5; kw++){
              const int xi = xx + kw - 2;
              if ((unsigned)xi < 8u) o[xx] = fmaf(w5[kw], rr[xi], o[xx]);
            }
          }
        }
      }
      const int nb = zy * 8;
      #pragma unroll
      for (int xx = 0; xx < 8; xx++){
        const size_t di = (size_t)(nb + xx)*HD_ + ch0 + ch;
        xabatch[di] += o[xx];            // coalesced across lanes (ch fastest)
      }
    }
    __syncthreads();   // before next half overwrites vol/wv
  }
}

// ---------------- proj GEMM, MFMA bf16 (unchanged from r9) ----------------
__global__ __launch_bounds__(256) void proj_kernel(
    const float* __restrict__ xa, const float* __restrict__ g,
    const float* __restrict__ Wp, const float* __restrict__ bp,
    float* __restrict__ out)
{
  __shared__ short As[128][40];
  __shared__ short Bs[128][40];

  const int tid  = threadIdx.x;
  const int row0 = blockIdx.y * 128;
  const int col0 = blockIdx.x * 128;
  const int wave = tid >> 6, lane = tid & 63;
  const int wm = (wave >> 1) * 64, wn = (wave & 1) * 64;
  const int fr = lane & 15, quad = lane >> 4;
  const int sr = tid >> 2;
  const int sk = (tid & 3) * 8;

  f32x4 acc[4][4] = {};

  for (int k0 = 0; k0 < C_; k0 += 32){
    #pragma unroll
    for (int half = 0; half < 2; half++){
      const int r = sr + half*64;
      const size_t aidx = (size_t)(row0 + r)*C_ + k0 + sk;
      float4 x0 = *reinterpret_cast<const float4*>(&xa[aidx]);
      float4 x1 = *reinterpret_cast<const float4*>(&xa[aidx + 4]);
      float4 g0 = *reinterpret_cast<const float4*>(&g[aidx]);
      float4 g1 = *reinterpret_cast<const float4*>(&g[aidx + 4]);
      x0.x*=g0.x; x0.y*=g0.y; x0.z*=g0.z; x0.w*=g0.w;
      x1.x*=g1.x; x1.y*=g1.y; x1.z*=g1.z; x1.w*=g1.w;
      const float* bp2 = &Wp[(size_t)(col0 + r)*C_ + k0 + sk];
      float4 b0 = *reinterpret_cast<const float4*>(bp2);
      float4 b1 = *reinterpret_cast<const float4*>(bp2 + 4);
      *reinterpret_cast<bfrag*>(&As[r][sk]) = cvt8(x0, x1);
      *reinterpret_cast<bfrag*>(&Bs[r][sk]) = cvt8(b0, b1);
    }
    __syncthreads();
    bfrag af[4], bf[4];
    #pragma unroll
    for (int f = 0; f < 4; f++){
      af[f] = *reinterpret_cast<const bfrag*>(&As[wm + f*16 + fr][quad*8]);
      bf[f] = *reinterpret_cast<const bfrag*>(&Bs[wn + f*16 + fr][quad*8]);
    }
    #pragma unroll
    for (int i=0;i<4;i++)
      #pragma unroll
      for (int j=0;j<4;j++)
        acc[i][j] = __builtin_amdgcn_mfma_f32_16x16x32_bf16(af[i], bf[j], acc[i][j], 0, 0, 0);
    __syncthreads();
  }

  #pragma unroll
  for (int i = 0; i < 4; i++){
    const int rowb = row0 + wm + i*16 + quad*4;
    #pragma unroll
    for (int j = 0; j < 4; j++){
      const int col = col0 + wn + j*16 + fr;
      const float bcol = bp[col];
      #pragma unroll
      for (int r = 0; r < 4; r++){
        out[(size_t)(rowb + r)*C_ + col] = acc[i][j][r] + bcol;
      }
    }
  }
}

extern "C" void kernel_launch(void* const* d_in, const int* in_sizes, int n_in,
                              void* d_out, int out_size, void* d_ws, size_t ws_size,
                              hipStream_t stream){
  float* out = (float*)d_out;

  const int expect[11] = {6291456, 6291456, 589824, 1536, 147456, 384, 8000, 64, 384, 384, 196608};
  bool ok = (n_in == 11);
  for (int i = 0; ok && i < 11; i++) ok = (in_sizes[i] == expect[i]);
  if (!ok){
    sentinel_kernel<<<(out_size+255)/256, 256, 0, stream>>>(out, out_size);
    return;
  }

  const float* x    = (const float*)d_in[0];
  const float* y    = (const float*)d_in[1];
  const float* W    = (const float*)d_in[2];
  const float* bq   = (const float*)d_in[3];
  const float* Wp   = (const float*)d_in[4];
  const float* bp   = (const float*)d_in[5];
  const float* dwcw = (const float*)d_in[6];
  const float* dwcb = (const float*)d_in[7];
  const float* pwp  = (const float*)d_in[8];
  const float* scp  = (const float*)d_in[9];
  const float* pe   = (const float*)d_in[10];

  float* ws = (float*)d_ws;
  const size_t SZ = (size_t)M_ * C_;
  float* q  = ws;
  float* k  = ws + SZ;
  float* v  = ws + 2*SZ;
  float* g  = ws + 3*SZ;
  float* xa = ws + 4*SZ;
  float* scale_inv = ws + 5*SZ;
  float* power     = scale_inv + 512;

  param_kernel<<<1, 512, 0, stream>>>(scp, pwp, scale_inv, power);
  gemm_qkvg<<<dim3(C_/128, M_/128, 4), 256, 0, stream>>>(x, y, W, bq, pe, scale_inv, q, k, v, g);
  attn_kernel<<<dim3(B_*H_), 512, 0, stream>>>(q, k, v, power, xa);
  conv_kernel<<<dim3(B_*H_), 512, 0, stream>>>(v, dwcw, dwcb, xa);
  proj_kernel<<<dim3(C_/128, M_/128), 256, 0, stream>>>(xa, g, Wp, bp, out);
}